// Round 1
// baseline (31.240 us; speedup 1.0000x reference)
//
#include <hip/hip_runtime.h>

// SigmoidLoss: out = sum_n mean_{s,t} [ softplus(z) - W[s,t]*z ],  z = f1[n,s]*f2[n,t]
// f1[n,s] = emb[bi, s, ei], f2[n,s] = emb[32+bi, s, ei],  n = bi*64 + ei
// W banded: W[s,t] = 1 - q/20, q = (t>=s ? t-s : s-t-1), zero for q >= 20.

#define SIDE 256
#define NB 32
#define NE 64
#define NROWS (NB * NE)  // 2048

__global__ __launch_bounds__(256) void sigloss_main(const float* __restrict__ emb,
                                                    float* __restrict__ partial) {
    const int n   = blockIdx.x;
    const int bi  = n >> 6;
    const int ei  = n & 63;
    const int tid = threadIdx.x;

    __shared__ float f1[SIDE];
    __shared__ float f2[SIDE];
    f1[tid] = emb[(size_t)bi * (SIDE * NE) + (size_t)tid * NE + ei];
    f2[tid] = emb[(size_t)(NB + bi) * (SIDE * NE) + (size_t)tid * NE + ei];
    __syncthreads();

    // ---- banded W-term: thread owns s = tid ----
    // g[s] = sum_{t in [s-20, s+19] ∩ [0,256)} (1 - 0.05*q) * f2[t]
    float g = 0.0f;
    {
        const int s  = tid;
        const int t0 = (s - 20 > 0) ? (s - 20) : 0;
        const int t1 = (s + 20 < SIDE) ? (s + 20) : SIDE;
        for (int t = t0; t < t1; ++t) {
            int d = t - s;
            int q = d ^ (d >> 31);   // d>=0 ? d : -d-1
            g = fmaf(1.0f - 0.05f * (float)q, f2[t], g);
        }
    }
    const float wterm = f1[tid] * g;

    // ---- softplus term: thread owns column t = tid ----
    // softplus(z) = ln2 * log2(1 + exp2(z*log2e)); pair two logs into one.
    const float c = f2[tid] * 1.4426950408889634f;  // fold log2(e) into f2[t]
    float accl = 0.0f;
    #pragma unroll 8
    for (int s = 0; s < SIDE; s += 2) {
        float e0 = __builtin_amdgcn_exp2f(f1[s]     * c);
        float e1 = __builtin_amdgcn_exp2f(f1[s + 1] * c);
        accl += __builtin_amdgcn_logf((1.0f + e0) * (1.0f + e1));  // v_log_f32 = log2
    }
    float val = accl * 0.6931471805599453f - wterm;

    // ---- block reduction (4 waves of 64) ----
    for (int off = 32; off > 0; off >>= 1) val += __shfl_down(val, off, 64);
    __shared__ float wsum[4];
    if ((tid & 63) == 0) wsum[tid >> 6] = val;
    __syncthreads();
    if (tid == 0) partial[n] = wsum[0] + wsum[1] + wsum[2] + wsum[3];
}

__global__ __launch_bounds__(256) void sigloss_reduce(const float* __restrict__ partial,
                                                      float* __restrict__ out) {
    const int tid = threadIdx.x;
    float v = 0.0f;
    #pragma unroll
    for (int i = tid; i < NROWS; i += 256) v += partial[i];
    for (int off = 32; off > 0; off >>= 1) v += __shfl_down(v, off, 64);
    __shared__ float wsum[4];
    if ((tid & 63) == 0) wsum[tid >> 6] = v;
    __syncthreads();
    if (tid == 0) out[0] = (wsum[0] + wsum[1] + wsum[2] + wsum[3]) * (1.0f / 65536.0f);
}

extern "C" void kernel_launch(void* const* d_in, const int* in_sizes, int n_in,
                              void* d_out, int out_size, void* d_ws, size_t ws_size,
                              hipStream_t stream) {
    const float* emb = (const float*)d_in[0];   // (64,256,64) f32
    float* partial = (float*)d_ws;              // 2048 floats scratch
    float* out = (float*)d_out;                 // 1 float
    sigloss_main<<<NROWS, 256, 0, stream>>>(emb, partial);
    sigloss_reduce<<<1, 256, 0, stream>>>(partial, out);
}